// Round 4
// baseline (2913.141 us; speedup 1.0000x reference)
//
#include <hip/hip_runtime.h>
#include <math.h>

#define B   64
#define T   512
#define I0  256
#define H   512
#define M   (B*T)

#define NGR 4             // batch groups (16 rows each -> MFMA M=16)
#define BGR 16
#define SLOT_US (B*H)     // 32768 us per slot (all groups)
#define GRP_US  (BGR*H)   // 8192 us per group region within a slot
#define RSLOTS0 64        // ring0 depth: L1 may lead L2 by up to ~48 steps
#define RESET_D0 8
#define RSLOTS1 8         // ring1 depth: L2 blocks self-sync to skew<=1
#define RESET_D1 4
#define RING0_US ((size_t)RSLOTS0*SLOT_US)   // 4MB
#define RING1_US ((size_t)RSLOTS1*SLOT_US)   // 512KB
#define LEAD_MAX 40       // back-pressure: L1 lead over L2 (< 64-8-skew)
#define POLL_BUDGET 2000000L

typedef __attribute__((ext_vector_type(8))) short short8;
typedef __attribute__((ext_vector_type(4))) float floatx4;
typedef unsigned long long u64;

static __device__ __forceinline__ unsigned short f2bf(float f) {
  unsigned u = __float_as_uint(f);
  u += 0x7fff + ((u >> 16) & 1);          // RNE
  return (unsigned short)(u >> 16);
}
static __device__ __forceinline__ float bf2f(unsigned short u) {
  return __uint_as_float((unsigned)u << 16);
}
// fast tanh: 1 - 2/(e^{2x}+1). |err| ~1e-6, saturates correctly at +/-1.
static __device__ __forceinline__ float ftanh(float x) {
  float e = __expf(2.0f * x);
  return 1.0f - 2.0f * __builtin_amdgcn_rcpf(e + 1.0f);
}
// nonzero iff any halfword of v == 0xFFFF (the bf16 sentinel)
static __device__ __forceinline__ u64 sentmask(u64 v) {
  u64 w = ~v;
  return (w - 0x0001000100010001ULL) & ~w & 0x8000800080008000ULL;
}

// ---------------------------------------------------------------------------
// fp32 GEMM for layer-1 input projection, bf16 output:
// xw[M,H] = bf16( x[M,I0] * Wih0[H,I0]^T )
// ---------------------------------------------------------------------------
template<int K>
__global__ __launch_bounds__(256)
void gemm_awt(const float* __restrict__ A, const float* __restrict__ W,
              unsigned short* __restrict__ C) {
  __shared__ float As[16][68];
  __shared__ float Bs[16][68];
  const int tid = threadIdx.x;
  const int tx = tid & 15, ty = tid >> 4;
  const int m0 = blockIdx.x * 64, n0 = blockIdx.y * 64;
  float acc[4][4] = {};
  for (int k0 = 0; k0 < K; k0 += 16) {
    {
      int e = tid * 4;
      int m = e >> 4, k = e & 15;
      float4 v = *(const float4*)&A[(m0 + m) * K + k0 + k];
      As[k][m] = v.x; As[k+1][m] = v.y; As[k+2][m] = v.z; As[k+3][m] = v.w;
      float4 w = *(const float4*)&W[(n0 + m) * K + k0 + k];
      Bs[k][m] = w.x; Bs[k+1][m] = w.y; Bs[k+2][m] = w.z; Bs[k+3][m] = w.w;
    }
    __syncthreads();
    #pragma unroll
    for (int k = 0; k < 16; ++k) {
      float a[4], w[4];
      *(float4*)a = *(const float4*)&As[k][ty*4];
      *(float4*)w = *(const float4*)&Bs[k][tx*4];
      #pragma unroll
      for (int i = 0; i < 4; ++i)
        #pragma unroll
        for (int j = 0; j < 4; ++j)
          acc[i][j] += a[i] * w[j];
    }
    __syncthreads();
  }
  #pragma unroll
  for (int i = 0; i < 4; ++i) {
    ushort4 r;
    r.x = f2bf(acc[i][0]); r.y = f2bf(acc[i][1]);
    r.z = f2bf(acc[i][2]); r.w = f2bf(acc[i][3]);
    *(ushort4*)&C[(size_t)(m0 + ty*4 + i) * H + n0 + tx*4] = r;
  }
}

// ---------------------------------------------------------------------------
// Pack [H,H] fp32 weight into bf16 B-fragment lane order:
// dst layout [tile=32][kt=16][lane=64][8 us]
// ---------------------------------------------------------------------------
__global__ __launch_bounds__(256)
void pack_w(const float* __restrict__ W, unsigned short* __restrict__ dst) {
  int idx = blockIdx.x * 256 + threadIdx.x;   // over 16*2*16*64 = 32768
  int l = idx & 63, i = (idx >> 6) & 15, tau = (idx >> 10) & 1, c = idx >> 11;
  int col = c * 32 + tau * 16 + (l & 15);
  int k0  = i * 32 + (l >> 4) * 8;
  const float* src = &W[col * H + k0];
  unsigned v[4];
  #pragma unroll
  for (int j = 0; j < 4; ++j) {
    unsigned lo = f2bf(src[2*j]);
    unsigned hi = f2bf(src[2*j + 1]);
    v[j] = lo | (hi << 16);
  }
  *(uint4*)&dst[(size_t)idx * 8] = make_uint4(v[0], v[1], v[2], v[3]);
}

// ---------------------------------------------------------------------------
// Free-running 4-wave recurrence. 64 blocks x 256 threads; block (g,wp) owns
// batch rows [16g,16g+16) and cols [32wp,32wp+32). Waves NEVER sync after
// init:
//   wave 0/1: layer 1, col tile 2wp+wv.   chain: poll ring0[r-1] -> 16 MFMA
//             (Whh0 in VGPRs) -> tanh(+xw) -> store ring0[r].
//   wave 2/3: layer 2, col tile 2wp+wv-2. chain: poll ring1[t-1] -> 16 MFMA
//             (Whh1 in VGPRs) -> + 16 MFMA (Wih1 from LDS, hv term, its
//             loads issued BEFORE the ring1 poll) -> tanh -> ring1[t]+dout.
// Rings are in MFMA A-FRAGMENT layout [slot][g][kt=16][lane=64][8 us]:
// consumer lane l reads contiguous 16B at (kt*64+l)*16B — fully coalesced,
// and the winning poll loads ARE the MFMA operands (no LDS, no barriers).
// Sentinel 0xFFFF (-NaN bf16; tanh can't produce it); each thread resets
// only its OWN addresses RESET_D slots ahead (same-thread same-addr =>
// ordered). ring0 is 64 deep so L1 free-runs ahead of L2; prog[] +
// back-pressure (lead <= 40, checked every 16 steps) bounds the lead below
// the recycle distance. L2 blocks mutually self-sync to skew<=1 through
// their full-group ring1 polls. Watchdog budgets bail instead of hanging.
// ---------------------------------------------------------------------------
__global__ __launch_bounds__(256, 1)
void rnn_fused(const unsigned short* __restrict__ xwb,  // [B][T][H] bf16
               const unsigned short* __restrict__ wp0,  // Whh0 packed
               const unsigned short* __restrict__ wp1,  // Wih1 packed
               const unsigned short* __restrict__ wp2,  // Whh1 packed
               unsigned short* __restrict__ ring0,      // [64][B][H] bf16
               unsigned short* __restrict__ ring1,      // [8][B][H] bf16
               float* __restrict__ dout,                // [B][T][H]
               int* __restrict__ prog)                  // [NGR][16]
{
  __shared__ unsigned short wi_lds[16384];   // Wih1 tile pair (32KB)
  const int tid  = threadIdx.x;
  const int wv   = tid >> 6;
  const int lane = tid & 63;
  const int mrow = lane & 15, quad = lane >> 4;
  const int g  = blockIdx.x & 3;
  const int wp = blockIdx.x >> 2;
  const int b0 = g * BGR;

  {   // stage Wih1 tile pair into LDS (only init-time sync in the kernel)
    const uint4* s = (const uint4*)(wp1 + (size_t)(2*wp) * 8192);
    uint4* d = (uint4*)wi_lds;
    for (int i = tid; i < 2048; i += 256) d[i] = s[i];
  }
  __syncthreads();

  const int tv   = 2*wp + (wv & 1);          // this wave's 16-col tile
  const int ccol = tv * 16 + mrow;
  // fragment-layout store offset for (row=quad*4+i, col=ccol):
  // off = wp*512 + ((wv&1)*2 + (mrow>>3))*128 + (mrow&7) + row*8
  const int soff = wp*512 + (((wv & 1)*2 + (mrow >> 3)) << 7) + (mrow & 7);
  long cnt = 0;

  if (wv < 2) {
    // ============================ layer 1 ============================
    short8 wa[16];
    #pragma unroll
    for (int kt = 0; kt < 16; ++kt)
      wa[kt] = *(const short8*)(wp0 + (size_t)((tv*16 + kt)*64 + lane) * 8);
    int* pg = prog + g * 16;

    for (int r = 0; r < T; ++r) {
      // xw operand loads (bf16) — issued before the poll, latency hidden
      unsigned short xus[4];
      #pragma unroll
      for (int i = 0; i < 4; ++i)
        xus[i] = xwb[((size_t)(b0 + quad*4 + i) * T + r) * H + ccol];

      u64 hv[32];
      if (r >= 1) {
        const u64* rb = (const u64*)(ring0
            + (size_t)((r-1) & (RSLOTS0-1)) * SLOT_US + g * GRP_US);
        for (;;) {
          #pragma unroll
          for (int kt = 0; kt < 16; ++kt) {
            hv[2*kt]   = __hip_atomic_load(rb + kt*128 + lane*2,
                                           __ATOMIC_RELAXED, __HIP_MEMORY_SCOPE_AGENT);
            hv[2*kt+1] = __hip_atomic_load(rb + kt*128 + lane*2 + 1,
                                           __ATOMIC_RELAXED, __HIP_MEMORY_SCOPE_AGENT);
          }
          u64 bad = 0;
          #pragma unroll
          for (int j = 0; j < 32; ++j) bad |= sentmask(hv[j]);
          if (__all(bad == 0) || ++cnt > POLL_BUDGET) break;
        }
      }
      floatx4 aA = {0.f,0.f,0.f,0.f}, aB = {0.f,0.f,0.f,0.f};
      if (r >= 1) {
        #pragma unroll
        for (int kt = 0; kt < 16; kt += 2) {   // 2 chains halve dep latency
          union { u64 u[2]; short8 s; } a, b;
          a.u[0] = hv[2*kt];   a.u[1] = hv[2*kt+1];
          b.u[0] = hv[2*kt+2]; b.u[1] = hv[2*kt+3];
          aA = __builtin_amdgcn_mfma_f32_16x16x32_bf16(a.s, wa[kt],   aA, 0, 0, 0);
          aB = __builtin_amdgcn_mfma_f32_16x16x32_bf16(b.s, wa[kt+1], aB, 0, 0, 0);
        }
      }
      unsigned short* wdst = ring0 + (size_t)(r & (RSLOTS0-1)) * SLOT_US + g*GRP_US;
      unsigned short* wrst = ring0 + (size_t)((r+RESET_D0) & (RSLOTS0-1)) * SLOT_US + g*GRP_US;
      #pragma unroll
      for (int i = 0; i < 4; ++i) {
        float h = ftanh(aA[i] + aB[i] + bf2f(xus[i]));
        __hip_atomic_store(wdst + soff + (quad*4 + i)*8, f2bf(h),
                           __ATOMIC_RELAXED, __HIP_MEMORY_SCOPE_AGENT);
      }
      #pragma unroll
      for (int i = 0; i < 4; ++i)
        __hip_atomic_store(wrst + soff + (quad*4 + i)*8, (unsigned short)0xFFFFu,
                           __ATOMIC_RELAXED, __HIP_MEMORY_SCOPE_AGENT);
      // back-pressure: keep lead below ring0 recycle distance
      if ((r & 15) == 0 && r) {
        for (;;) {
          int mn = 0x7fffffff;
          #pragma unroll
          for (int j = 0; j < 16; ++j) {
            int v = __hip_atomic_load(pg + j, __ATOMIC_RELAXED, __HIP_MEMORY_SCOPE_AGENT);
            mn = v < mn ? v : mn;
          }
          if (r - mn <= LEAD_MAX || ++cnt > POLL_BUDGET) break;
          __builtin_amdgcn_s_sleep(8);
        }
      }
    }
  } else {
    // ============================ layer 2 ============================
    short8 wb[16];
    #pragma unroll
    for (int kt = 0; kt < 16; ++kt)
      wb[kt] = *(const short8*)(wp2 + (size_t)((tv*16 + kt)*64 + lane) * 8);
    const unsigned short* wil = wi_lds + (size_t)(wv & 1) * 8192;
    int* ps = prog + g * 16 + wp;

    for (int t = 0; t < T; ++t) {
      // issue h1[t] loads first (L1 leads, so usually already clean);
      // their latency hides under the ring1 poll + Whh1 MFMAs
      u64 hv[32];
      const u64* rb0 = (const u64*)(ring0
          + (size_t)(t & (RSLOTS0-1)) * SLOT_US + g * GRP_US);
      #pragma unroll
      for (int kt = 0; kt < 16; ++kt) {
        hv[2*kt]   = __hip_atomic_load(rb0 + kt*128 + lane*2,
                                       __ATOMIC_RELAXED, __HIP_MEMORY_SCOPE_AGENT);
        hv[2*kt+1] = __hip_atomic_load(rb0 + kt*128 + lane*2 + 1,
                                       __ATOMIC_RELAXED, __HIP_MEMORY_SCOPE_AGENT);
      }
      // serial chain: poll own-layer recurrence ring1[t-1]
      u64 gv[32];
      if (t >= 1) {
        const u64* rb1 = (const u64*)(ring1
            + (size_t)((t-1) & (RSLOTS1-1)) * SLOT_US + g * GRP_US);
        for (;;) {
          #pragma unroll
          for (int kt = 0; kt < 16; ++kt) {
            gv[2*kt]   = __hip_atomic_load(rb1 + kt*128 + lane*2,
                                           __ATOMIC_RELAXED, __HIP_MEMORY_SCOPE_AGENT);
            gv[2*kt+1] = __hip_atomic_load(rb1 + kt*128 + lane*2 + 1,
                                           __ATOMIC_RELAXED, __HIP_MEMORY_SCOPE_AGENT);
          }
          u64 bad = 0;
          #pragma unroll
          for (int j = 0; j < 32; ++j) bad |= sentmask(gv[j]);
          if (__all(bad == 0) || ++cnt > POLL_BUDGET) break;
        }
      }
      floatx4 pa = {0.f,0.f,0.f,0.f}, pb = {0.f,0.f,0.f,0.f};
      floatx4 pc = {0.f,0.f,0.f,0.f}, pd = {0.f,0.f,0.f,0.f};
      if (t >= 1) {
        #pragma unroll
        for (int kt = 0; kt < 16; kt += 2) {
          union { u64 u[2]; short8 s; } a, b;
          a.u[0] = gv[2*kt];   a.u[1] = gv[2*kt+1];
          b.u[0] = gv[2*kt+2]; b.u[1] = gv[2*kt+3];
          pa = __builtin_amdgcn_mfma_f32_16x16x32_bf16(a.s, wb[kt],   pa, 0, 0, 0);
          pb = __builtin_amdgcn_mfma_f32_16x16x32_bf16(b.s, wb[kt+1], pb, 0, 0, 0);
        }
      }
      // verify hv clean (rare loop — L1 leads); then Wih1 term from LDS
      for (;;) {
        u64 bad = 0;
        #pragma unroll
        for (int j = 0; j < 32; ++j) bad |= sentmask(hv[j]);
        if (__all(bad == 0) || ++cnt > POLL_BUDGET) break;
        #pragma unroll
        for (int kt = 0; kt < 16; ++kt) {
          hv[2*kt]   = __hip_atomic_load(rb0 + kt*128 + lane*2,
                                         __ATOMIC_RELAXED, __HIP_MEMORY_SCOPE_AGENT);
          hv[2*kt+1] = __hip_atomic_load(rb0 + kt*128 + lane*2 + 1,
                                         __ATOMIC_RELAXED, __HIP_MEMORY_SCOPE_AGENT);
        }
      }
      #pragma unroll
      for (int kt = 0; kt < 16; kt += 2) {
        union { u64 u[2]; short8 s; } a, b;
        a.u[0] = hv[2*kt];   a.u[1] = hv[2*kt+1];
        b.u[0] = hv[2*kt+2]; b.u[1] = hv[2*kt+3];
        short8 w0 = *(const short8*)(wil + ((size_t)(kt*64     + lane)) * 8);
        short8 w1 = *(const short8*)(wil + ((size_t)((kt+1)*64 + lane)) * 8);
        pc = __builtin_amdgcn_mfma_f32_16x16x32_bf16(a.s, w0, pc, 0, 0, 0);
        pd = __builtin_amdgcn_mfma_f32_16x16x32_bf16(b.s, w1, pd, 0, 0, 0);
      }
      unsigned short* wdst = ring1 + (size_t)(t & (RSLOTS1-1)) * SLOT_US + g*GRP_US;
      unsigned short* wrst = ring1 + (size_t)((t+RESET_D1) & (RSLOTS1-1)) * SLOT_US + g*GRP_US;
      #pragma unroll
      for (int i = 0; i < 4; ++i) {
        float v = ftanh(pa[i] + pb[i] + pc[i] + pd[i]);
        __hip_atomic_store(wdst + soff + (quad*4 + i)*8, f2bf(v),
                           __ATOMIC_RELAXED, __HIP_MEMORY_SCOPE_AGENT);
        dout[((size_t)(b0 + quad*4 + i) * T + t) * H + ccol] = v;
      }
      #pragma unroll
      for (int i = 0; i < 4; ++i)
        __hip_atomic_store(wrst + soff + (quad*4 + i)*8, (unsigned short)0xFFFFu,
                           __ATOMIC_RELAXED, __HIP_MEMORY_SCOPE_AGENT);
      if ((t & 7) == 0 && wv == 2 && lane == 0)
        __hip_atomic_store(ps, t, __ATOMIC_RELAXED, __HIP_MEMORY_SCOPE_AGENT);
    }
  }
}

extern "C" void kernel_launch(void* const* d_in, const int* in_sizes, int n_in,
                              void* d_out, int out_size, void* d_ws, size_t ws_size,
                              hipStream_t stream) {
  const float* x    = (const float*)d_in[0];
  const float* Wih0 = (const float*)d_in[1];
  const float* Whh0 = (const float*)d_in[2];
  const float* Wih1 = (const float*)d_in[3];
  const float* Whh1 = (const float*)d_in[4];
  float* out = (float*)d_out;

  char* ws = (char*)d_ws;
  unsigned short* xwb = (unsigned short*)ws;                        // 32MB
  unsigned short* wp0 = (unsigned short*)(ws + (size_t)32*1024*1024);
  unsigned short* wp1 = (unsigned short*)(ws + (size_t)32*1024*1024 + 512*1024);
  unsigned short* wp2 = (unsigned short*)(ws + (size_t)32*1024*1024 + 1024*1024);
  unsigned short* ring0 = (unsigned short*)(ws + (size_t)32*1024*1024 + 1536*1024);
  unsigned short* ring1 = ring0 + RING0_US;
  int* prog = (int*)(ring1 + RING1_US);

  // sentinel-fill both rings; zero the progress array
  hipMemsetAsync(ring0, 0xFF, (RING0_US + RING1_US) * sizeof(unsigned short), stream);
  hipMemsetAsync(prog, 0, NGR * 16 * sizeof(int), stream);

  pack_w<<<128, 256, 0, stream>>>(Whh0, wp0);
  pack_w<<<128, 256, 0, stream>>>(Wih1, wp1);
  pack_w<<<128, 256, 0, stream>>>(Whh1, wp2);

  dim3 gg(M/64, H/64);
  gemm_awt<I0><<<gg, 256, 0, stream>>>(x, Wih0, xwb);

  rnn_fused<<<NGR * 16, 256, 0, stream>>>(
      xwb, wp0, wp1, wp2, ring0, ring1, out, prog);
}

// Round 5
// 2253.895 us; speedup vs baseline: 1.2925x; 1.2925x over previous
//
#include <hip/hip_runtime.h>
#include <math.h>

#define B   64
#define T   512
#define I0  256
#define H   512
#define M   (B*T)

#define NGR 4             // batch groups (16 rows each -> MFMA M=16)
#define BGR 16
#define RSLOTS 8          // ring depth (power of 2)
#define RESET_D 4         // sentinel re-arm distance (slot s armed at round s-4)
#define SLOT_US (B*H)     // 32768 us per slot
#define GRP_US  (BGR*H)   // 8192 us per group region
#define RING_US ((size_t)RSLOTS*SLOT_US)   // 512KB per ring
#define POLL_BUDGET 2000000L

typedef __attribute__((ext_vector_type(8))) short short8;
typedef __attribute__((ext_vector_type(4))) float floatx4;
typedef __attribute__((ext_vector_type(2))) unsigned long long u64x2;
typedef unsigned long long u64;

static __device__ __forceinline__ unsigned short f2bf(float f) {
  unsigned u = __float_as_uint(f);
  u += 0x7fff + ((u >> 16) & 1);          // RNE
  return (unsigned short)(u >> 16);
}
static __device__ __forceinline__ float bf2f(unsigned short u) {
  return __uint_as_float((unsigned)u << 16);
}
// fast tanh: 1 - 2/(e^{2x}+1). |err| ~1e-6, saturates correctly at +/-1.
static __device__ __forceinline__ float ftanh(float x) {
  float e = __expf(2.0f * x);
  return 1.0f - 2.0f * __builtin_amdgcn_rcpf(e + 1.0f);
}
// nonzero iff any halfword of v == 0xFFFF (the bf16 sentinel)
static __device__ __forceinline__ u64 sentmask(u64 v) {
  u64 w = ~v;
  return (w - 0x0001000100010001ULL) & ~w & 0x8000800080008000ULL;
}

// ---------------------------------------------------------------------------
// fp32 GEMM for layer-1 input projection, bf16 output:
// xw[M,H] = bf16( x[M,I0] * Wih0[H,I0]^T )
// ---------------------------------------------------------------------------
template<int K>
__global__ __launch_bounds__(256)
void gemm_awt(const float* __restrict__ A, const float* __restrict__ W,
              unsigned short* __restrict__ C) {
  __shared__ float As[16][68];
  __shared__ float Bs[16][68];
  const int tid = threadIdx.x;
  const int tx = tid & 15, ty = tid >> 4;
  const int m0 = blockIdx.x * 64, n0 = blockIdx.y * 64;
  float acc[4][4] = {};
  for (int k0 = 0; k0 < K; k0 += 16) {
    {
      int e = tid * 4;
      int m = e >> 4, k = e & 15;
      float4 v = *(const float4*)&A[(m0 + m) * K + k0 + k];
      As[k][m] = v.x; As[k+1][m] = v.y; As[k+2][m] = v.z; As[k+3][m] = v.w;
      float4 w = *(const float4*)&W[(n0 + m) * K + k0 + k];
      Bs[k][m] = w.x; Bs[k+1][m] = w.y; Bs[k+2][m] = w.z; Bs[k+3][m] = w.w;
    }
    __syncthreads();
    #pragma unroll
    for (int k = 0; k < 16; ++k) {
      float a[4], w[4];
      *(float4*)a = *(const float4*)&As[k][ty*4];
      *(float4*)w = *(const float4*)&Bs[k][tx*4];
      #pragma unroll
      for (int i = 0; i < 4; ++i)
        #pragma unroll
        for (int j = 0; j < 4; ++j)
          acc[i][j] += a[i] * w[j];
    }
    __syncthreads();
  }
  #pragma unroll
  for (int i = 0; i < 4; ++i) {
    ushort4 r;
    r.x = f2bf(acc[i][0]); r.y = f2bf(acc[i][1]);
    r.z = f2bf(acc[i][2]); r.w = f2bf(acc[i][3]);
    *(ushort4*)&C[(size_t)(m0 + ty*4 + i) * H + n0 + tx*4] = r;
  }
}

// ---------------------------------------------------------------------------
// Pack [H,H] fp32 weight into bf16 B-fragment lane order:
// dst layout [tile=32][kt=16][lane=64][8 us]
// ---------------------------------------------------------------------------
__global__ __launch_bounds__(256)
void pack_w(const float* __restrict__ W, unsigned short* __restrict__ dst) {
  int idx = blockIdx.x * 256 + threadIdx.x;   // over 16*2*16*64 = 32768
  int l = idx & 63, i = (idx >> 6) & 15, tau = (idx >> 10) & 1, c = idx >> 11;
  int col = c * 32 + tau * 16 + (l & 15);
  int k0  = i * 32 + (l >> 4) * 8;
  const float* src = &W[col * H + k0];
  unsigned v[4];
  #pragma unroll
  for (int j = 0; j < 4; ++j) {
    unsigned lo = f2bf(src[2*j]);
    unsigned hi = f2bf(src[2*j + 1]);
    v[j] = lo | (hi << 16);
  }
  *(uint4*)&dst[(size_t)idx * 8] = make_uint4(v[0], v[1], v[2], v[3]);
}

// ---------------------------------------------------------------------------
// Lockstep recurrence, minimal critical path. 64 blocks x 256 thr; block
// (g,wp) owns batch rows [16g,16g+16), cols [32wp,32wp+32), both layers.
// Rings in MFMA A-FRAGMENT layout [slot][g][kt=16][lane=64][8 us]
// (HW-verified in round 4): fragment poll loads ARE the MFMA operands.
// Round r (one raw s_barrier at the END, nothing else):
//   waves 0/1 (L1): poll ring0[r-1] per-lane (the ONLY blocking wait) ->
//     16 MFMA (Whh0, B-frags from LDS) -> ftanh(+xw) -> store ring0[r]
//     -> ds_write polled hv to hs[(r-1)&1] for L2's next round.
//   waves 2/3 (L2, t=r-2): 16 MFMA (Wih1, A from hs[r&1] = h1[t]) ->
//     check prefetched gv (=h2[t-1], fetched across the barrier last round,
//     ~always clean) -> 16 MFMA (Whh1) -> ftanh -> ring1[t] + dout ->
//     prefetch next gv. L2 never blocks the round.
// Sentinel 0xFFFF (-NaN bf16); each thread re-arms only its OWN addresses
// RESET_D slots ahead (same-thread same-addr => ordered). Lockstep skew<=1
// is enforced by the L1 poll itself; all reset/read distances safe at
// skew<=1. Poll budget bails instead of hanging.
// ---------------------------------------------------------------------------
__global__ __launch_bounds__(256, 1)
void rnn_fused(const unsigned short* __restrict__ xwb,  // [B][T][H] bf16
               const unsigned short* __restrict__ wp0,  // Whh0 packed
               const unsigned short* __restrict__ wp1,  // Wih1 packed
               const unsigned short* __restrict__ wp2,  // Whh1 packed
               unsigned short* __restrict__ ring0,      // [8][B][H] bf16
               unsigned short* __restrict__ ring1,      // [8][B][H] bf16
               float* __restrict__ dout)                // [B][T][H]
{
  extern __shared__ unsigned short smem[];
  unsigned short* Ws0 = smem;             // [2][16][64][8] = 16384 us
  unsigned short* Wi1 = Ws0 + 16384;
  unsigned short* Ws1 = Wi1 + 16384;
  unsigned short* hs  = Ws1 + 16384;      // [2][16][64][8] dbuf, frag layout

  const int tid  = threadIdx.x;
  const int wv   = tid >> 6;
  const int lane = tid & 63;
  const int mrow = lane & 15, quad = lane >> 4;
  const int g  = blockIdx.x & 3;
  const int wp = blockIdx.x >> 2;
  const int b0 = g * BGR;

  {   // stage packed weight tile-pairs
    const uint4* s0 = (const uint4*)(wp0 + (size_t)(2*wp) * 8192);
    const uint4* s1 = (const uint4*)(wp1 + (size_t)(2*wp) * 8192);
    const uint4* s2 = (const uint4*)(wp2 + (size_t)(2*wp) * 8192);
    uint4* d0 = (uint4*)Ws0; uint4* d1 = (uint4*)Wi1; uint4* d2 = (uint4*)Ws1;
    for (int i = tid; i < 2048; i += 256) { d0[i] = s0[i]; d1[i] = s1[i]; d2[i] = s2[i]; }
  }
  __syncthreads();

  const int tau  = wv & 1;                 // tile within this block's pair
  const int tv   = 2*wp + tau;
  const int ccol = tv*16 + mrow;
  // fragment-layout store offset for (row=quad*4+i, col=ccol) [R4-verified]
  const int soff = wp*512 + ((tau*2 + (mrow >> 3)) << 7) + (mrow & 7);
  long cnt = 0;
  u64 gv[32];                              // L2's prefetched h2[t-1] frags

  for (int r = 0; r <= T + 1; ++r) {
    if (wv < 2) {
      // ========================= layer 1 =========================
      unsigned short xus[4];
      if (r < T) {
        #pragma unroll
        for (int i = 0; i < 4; ++i)
          xus[i] = xwb[((size_t)(b0 + quad*4 + i) * T + r) * H + ccol];
      }
      u64 hv[32];
      if (r >= 1 && r <= T) {
        const u64* rb = (const u64*)(ring0
            + (size_t)((r-1) & (RSLOTS-1)) * SLOT_US + g * GRP_US);
        for (;;) {          // per-lane fragment poll: winning loads = operands
          #pragma unroll
          for (int kt = 0; kt < 16; ++kt) {
            hv[2*kt]   = __hip_atomic_load(rb + kt*128 + lane*2,
                                           __ATOMIC_RELAXED, __HIP_MEMORY_SCOPE_AGENT);
            hv[2*kt+1] = __hip_atomic_load(rb + kt*128 + lane*2 + 1,
                                           __ATOMIC_RELAXED, __HIP_MEMORY_SCOPE_AGENT);
          }
          u64 bad = 0;
          #pragma unroll
          for (int j = 0; j < 32; ++j) bad |= sentmask(hv[j]);
          if (bad == 0 || ++cnt > POLL_BUDGET) break;
        }
      }
      if (r < T) {
        floatx4 aA = {0.f,0.f,0.f,0.f}, aB = {0.f,0.f,0.f,0.f};
        if (r >= 1) {
          const unsigned short* wsl = Ws0 + tau * 8192;
          #pragma unroll
          for (int kt = 0; kt < 16; kt += 2) {
            union { u64 u[2]; short8 s; } a, b;
            a.u[0] = hv[2*kt];   a.u[1] = hv[2*kt+1];
            b.u[0] = hv[2*kt+2]; b.u[1] = hv[2*kt+3];
            short8 w0 = *(const short8*)(wsl + ((kt  )*64 + lane)*8);
            short8 w1 = *(const short8*)(wsl + ((kt+1)*64 + lane)*8);
            aA = __builtin_amdgcn_mfma_f32_16x16x32_bf16(a.s, w0, aA, 0, 0, 0);
            aB = __builtin_amdgcn_mfma_f32_16x16x32_bf16(b.s, w1, aB, 0, 0, 0);
          }
        }
        unsigned short* wdst = ring0 + (size_t)(r & (RSLOTS-1)) * SLOT_US + g*GRP_US;
        unsigned short* wrst = ring0 + (size_t)((r+RESET_D) & (RSLOTS-1)) * SLOT_US + g*GRP_US;
        #pragma unroll
        for (int i = 0; i < 4; ++i) {
          float h = ftanh(aA[i] + aB[i] + bf2f(xus[i]));
          __hip_atomic_store(wdst + soff + (quad*4 + i)*8, f2bf(h),
                             __ATOMIC_RELAXED, __HIP_MEMORY_SCOPE_AGENT);
        }
        #pragma unroll
        for (int i = 0; i < 4; ++i)     // re-arm own sentinel addrs
          __hip_atomic_store(wrst + soff + (quad*4 + i)*8, (unsigned short)0xFFFFu,
                             __ATOMIC_RELAXED, __HIP_MEMORY_SCOPE_AGENT);
      }
      if (r >= 1 && r <= T) {
        // share polled h1[r-1] with L2 waves (consumed NEXT round)
        unsigned short* hb = hs + (size_t)((r-1) & 1) * 8192;
        if (wv == 0) {
          #pragma unroll
          for (int k8 = 0; k8 < 8; ++k8) {
            u64x2 v; v.x = hv[2*k8]; v.y = hv[2*k8 + 1];
            *(u64x2*)(hb + ((size_t)k8*64 + lane)*8) = v;
          }
        } else {
          #pragma unroll
          for (int k8 = 0; k8 < 8; ++k8) {
            u64x2 v; v.x = hv[16 + 2*k8]; v.y = hv[16 + 2*k8 + 1];
            *(u64x2*)(hb + ((size_t)(8 + k8)*64 + lane)*8) = v;
          }
        }
      }
    } else {
      // ========================= layer 2 (t = r-2) =========================
      if (r >= 2) {
        const int t = r - 2;
        const unsigned short* hb  = hs  + (size_t)(r & 1) * 8192;   // h1[t]
        const unsigned short* wil = Wi1 + tau * 8192;
        const unsigned short* whl = Ws1 + tau * 8192;
        floatx4 pa = {0.f,0.f,0.f,0.f}, pb = {0.f,0.f,0.f,0.f};
        #pragma unroll
        for (int kt = 0; kt < 16; kt += 2) {       // Wih1 * h1[t] (LDS)
          union { u64 u[2]; short8 s; } a, b;
          u64x2 va = *(const u64x2*)(hb + ((size_t)(kt  )*64 + lane)*8);
          u64x2 vb = *(const u64x2*)(hb + ((size_t)(kt+1)*64 + lane)*8);
          a.u[0] = va.x; a.u[1] = va.y; b.u[0] = vb.x; b.u[1] = vb.y;
          short8 w0 = *(const short8*)(wil + ((kt  )*64 + lane)*8);
          short8 w1 = *(const short8*)(wil + ((kt+1)*64 + lane)*8);
          pa = __builtin_amdgcn_mfma_f32_16x16x32_bf16(a.s, w0, pa, 0, 0, 0);
          pb = __builtin_amdgcn_mfma_f32_16x16x32_bf16(b.s, w1, pb, 0, 0, 0);
        }
        if (t >= 1) {
          // verify prefetched gv (= h2[t-1]); stored >=1 round ago -> rare loop
          const u64* rb1 = (const u64*)(ring1
              + (size_t)((r-3) & (RSLOTS-1)) * SLOT_US + g * GRP_US);
          for (;;) {
            u64 bad = 0;
            #pragma unroll
            for (int j = 0; j < 32; ++j) bad |= sentmask(gv[j]);
            if (bad == 0 || ++cnt > POLL_BUDGET) break;
            #pragma unroll
            for (int kt = 0; kt < 16; ++kt) {
              gv[2*kt]   = __hip_atomic_load(rb1 + kt*128 + lane*2,
                                             __ATOMIC_RELAXED, __HIP_MEMORY_SCOPE_AGENT);
              gv[2*kt+1] = __hip_atomic_load(rb1 + kt*128 + lane*2 + 1,
                                             __ATOMIC_RELAXED, __HIP_MEMORY_SCOPE_AGENT);
            }
          }
          #pragma unroll
          for (int kt = 0; kt < 16; kt += 2) {     // Whh1 * h2[t-1]
            union { u64 u[2]; short8 s; } a, b;
            a.u[0] = gv[2*kt];   a.u[1] = gv[2*kt+1];
            b.u[0] = gv[2*kt+2]; b.u[1] = gv[2*kt+3];
            short8 w0 = *(const short8*)(whl + ((kt  )*64 + lane)*8);
            short8 w1 = *(const short8*)(whl + ((kt+1)*64 + lane)*8);
            pa = __builtin_amdgcn_mfma_f32_16x16x32_bf16(a.s, w0, pa, 0, 0, 0);
            pb = __builtin_amdgcn_mfma_f32_16x16x32_bf16(b.s, w1, pb, 0, 0, 0);
          }
        }
        unsigned short* wdst = ring1 + (size_t)(t & (RSLOTS-1)) * SLOT_US + g*GRP_US;
        unsigned short* wrst = ring1 + (size_t)((t+RESET_D) & (RSLOTS-1)) * SLOT_US + g*GRP_US;
        #pragma unroll
        for (int i = 0; i < 4; ++i) {
          float v = ftanh(pa[i] + pb[i]);
          __hip_atomic_store(wdst + soff + (quad*4 + i)*8, f2bf(v),
                             __ATOMIC_RELAXED, __HIP_MEMORY_SCOPE_AGENT);
          dout[((size_t)(b0 + quad*4 + i) * T + t) * H + ccol] = v;
        }
        #pragma unroll
        for (int i = 0; i < 4; ++i)
          __hip_atomic_store(wrst + soff + (quad*4 + i)*8, (unsigned short)0xFFFFu,
                             __ATOMIC_RELAXED, __HIP_MEMORY_SCOPE_AGENT);
        if (r <= T) {
          // prefetch gv for next round (h2[t] = slot just written this round);
          // loads fly across the barrier, checked at next use
          const u64* rbn = (const u64*)(ring1
              + (size_t)((r-2) & (RSLOTS-1)) * SLOT_US + g * GRP_US);
          #pragma unroll
          for (int kt = 0; kt < 16; ++kt) {
            gv[2*kt]   = __hip_atomic_load(rbn + kt*128 + lane*2,
                                           __ATOMIC_RELAXED, __HIP_MEMORY_SCOPE_AGENT);
            gv[2*kt+1] = __hip_atomic_load(rbn + kt*128 + lane*2 + 1,
                                           __ATOMIC_RELAXED, __HIP_MEMORY_SCOPE_AGENT);
          }
        }
      }
    }
    // one barrier per round; drain LDS writes only (never vmcnt)
    asm volatile("s_waitcnt lgkmcnt(0)\n\ts_barrier" ::: "memory");
    __builtin_amdgcn_sched_barrier(0);
  }
}

#define SMEM_BYTES ((3 * 16384 + 2 * 8192) * 2)   // 131072

extern "C" void kernel_launch(void* const* d_in, const int* in_sizes, int n_in,
                              void* d_out, int out_size, void* d_ws, size_t ws_size,
                              hipStream_t stream) {
  const float* x    = (const float*)d_in[0];
  const float* Wih0 = (const float*)d_in[1];
  const float* Whh0 = (const float*)d_in[2];
  const float* Wih1 = (const float*)d_in[3];
  const float* Whh1 = (const float*)d_in[4];
  float* out = (float*)d_out;

  char* ws = (char*)d_ws;
  unsigned short* xwb = (unsigned short*)ws;                        // 32MB
  unsigned short* wp0 = (unsigned short*)(ws + (size_t)32*1024*1024);
  unsigned short* wp1 = (unsigned short*)(ws + (size_t)32*1024*1024 + 512*1024);
  unsigned short* wp2 = (unsigned short*)(ws + (size_t)32*1024*1024 + 1024*1024);
  unsigned short* ring0 = (unsigned short*)(ws + (size_t)32*1024*1024 + 1536*1024);
  unsigned short* ring1 = ring0 + RING_US;

  // sentinel-fill both rings (0xFFFF bf16 = -NaN; tanh never produces it)
  hipMemsetAsync(ring0, 0xFF, 2 * RING_US * sizeof(unsigned short), stream);
  hipFuncSetAttribute((const void*)rnn_fused,
                      hipFuncAttributeMaxDynamicSharedMemorySize, SMEM_BYTES);

  pack_w<<<128, 256, 0, stream>>>(Whh0, wp0);
  pack_w<<<128, 256, 0, stream>>>(Wih1, wp1);
  pack_w<<<128, 256, 0, stream>>>(Whh1, wp2);

  dim3 gg(M/64, H/64);
  gemm_awt<I0><<<gg, 256, 0, stream>>>(x, Wih0, xwb);

  rnn_fused<<<NGR * 16, 256, SMEM_BYTES, stream>>>(
      xwb, wp0, wp1, wp2, ring0, ring1, out);
}